// Round 1
// baseline (583.657 us; speedup 1.0000x reference)
//
#include <hip/hip_runtime.h>
#include <hip/hip_bf16.h>
#include <math.h>

#define NN 100000
#define NE 3200000
#define CF 512

// ---- ws layout (bytes) ----
// [0,        409600)  : deg  (int[NN])
// [409600,   819200)  : s    (float[NN])   -- edge-sum accumulator
// [819200,  1228800)  : g    (float[NN])   -- h[i]*dinv[i]
// [1228800, 1638400)  : dinv (float[NN])
// [1638400, 1638404)  : flag (int)         -- 1 if edge_index is int64
#define OFF_S    409600
#define OFF_G    819200
#define OFF_DINV 1228800
#define OFF_FLAG 1638400

// Detect whether edge_index buffer is int64 (values < 2^31 => all high words 0)
__global__ void detect_i64_kernel(const unsigned int* e32, int* flag) {
    unsigned v = e32[2 * threadIdx.x + 1];
    unsigned long long m = __ballot(v != 0u);
    if (threadIdx.x == 0) *flag = (m == 0ULL) ? 1 : 0;
}

// In-degree histogram over targets (col = edge_index[1])
__global__ void deg_kernel(const int* __restrict__ e32,
                           const long long* __restrict__ e64,
                           const int* __restrict__ flag,
                           int* __restrict__ deg) {
    int e = blockIdx.x * blockDim.x + threadIdx.x;
    if (e >= NE) return;
    int col = (*flag) ? (int)e64[NE + e] : e32[NE + e];
    atomicAdd(&deg[col], 1);
}

// One wave (64 lanes) per node: h = dot(x[i,:], W), g = h * dinv, store dinv
__global__ __launch_bounds__(256) void node_kernel(const float* __restrict__ x,
                                                   const float* __restrict__ W,
                                                   const int* __restrict__ deg,
                                                   float* __restrict__ g,
                                                   float* __restrict__ dinv) {
    int wave = (int)((blockIdx.x * blockDim.x + threadIdx.x) >> 6);
    int lane = threadIdx.x & 63;
    if (wave >= NN) return;
    const float4* xr = (const float4*)(x + (size_t)wave * CF);
    const float4* Wr = (const float4*)W;
    float sum = 0.f;
#pragma unroll
    for (int j = 0; j < 2; ++j) {
        float4 a = xr[lane + 64 * j];
        float4 w = Wr[lane + 64 * j];
        sum += a.x * w.x + a.y * w.y + a.z * w.z + a.w * w.w;
    }
#pragma unroll
    for (int off = 32; off >= 1; off >>= 1)
        sum += __shfl_down(sum, off, 64);
    if (lane == 0) {
        float dv = rsqrtf((float)(deg[wave] + 1));  // +1 self-loop
        dinv[wave] = dv;
        g[wave] = sum * dv;
    }
}

// Per-edge scatter: s[col] += g[row]
__global__ void scatter_kernel(const int* __restrict__ e32,
                               const long long* __restrict__ e64,
                               const int* __restrict__ flag,
                               const float* __restrict__ g,
                               float* __restrict__ s) {
    int e = blockIdx.x * blockDim.x + threadIdx.x;
    if (e >= NE) return;
    int row, col;
    if (*flag) {
        row = (int)e64[e];
        col = (int)e64[NE + e];
    } else {
        row = e32[e];
        col = e32[NE + e];
    }
    atomicAdd(&s[col], g[row]);
}

// out[i] = sigmoid(dinv[i]*(s[i] + g[i]) + b)
__global__ void final_kernel(const float* __restrict__ s,
                             const float* __restrict__ g,
                             const float* __restrict__ dinv,
                             const float* __restrict__ b,
                             float* __restrict__ out) {
    int i = blockIdx.x * blockDim.x + threadIdx.x;
    if (i >= NN) return;
    float v = dinv[i] * (s[i] + g[i]) + b[0];
    out[i] = 1.f / (1.f + expf(-v));
}

extern "C" void kernel_launch(void* const* d_in, const int* in_sizes, int n_in,
                              void* d_out, int out_size, void* d_ws, size_t ws_size,
                              hipStream_t stream) {
    const float* x = (const float*)d_in[0];
    const void* eidx = d_in[1];
    const float* W = (const float*)d_in[2];
    const float* b = (const float*)d_in[3];
    float* out = (float*)d_out;

    char* ws = (char*)d_ws;
    int* deg = (int*)(ws);
    float* s = (float*)(ws + OFF_S);
    float* g = (float*)(ws + OFF_G);
    float* dinv = (float*)(ws + OFF_DINV);
    int* flag = (int*)(ws + OFF_FLAG);

    // zero deg + s accumulators (ws is re-poisoned to 0xAA before every call)
    hipMemsetAsync(d_ws, 0, OFF_G, stream);

    detect_i64_kernel<<<1, 64, 0, stream>>>((const unsigned int*)eidx, flag);
    deg_kernel<<<(NE + 255) / 256, 256, 0, stream>>>(
        (const int*)eidx, (const long long*)eidx, flag, deg);
    node_kernel<<<(NN * 64 + 255) / 256, 256, 0, stream>>>(x, W, deg, g, dinv);
    scatter_kernel<<<(NE + 255) / 256, 256, 0, stream>>>(
        (const int*)eidx, (const long long*)eidx, flag, g, s);
    final_kernel<<<(NN + 255) / 256, 256, 0, stream>>>(s, g, dinv, b, out);
}

// Round 2
// 569.808 us; speedup vs baseline: 1.0243x; 1.0243x over previous
//
#include <hip/hip_runtime.h>
#include <hip/hip_bf16.h>
#include <math.h>

#define NN 100000
#define NE 3200000
#define CF 512
#define NREP 8

// ---- ws layout (bytes) ----
// deg_r : int  [NREP][NN]  @ 0          (3,200,000)
// s_r   : float[NREP][NN]  @ 3,200,000  (3,200,000)
// g     : float[NN]        @ 6,400,000
// dinv  : float[NN]        @ 6,800,000
// flag  : int              @ 7,200,000
#define OFF_S    3200000
#define OFF_G    6400000
#define OFF_DINV 6800000
#define OFF_FLAG 7200000

// Physical XCD id (0..7). HW_REG_XCC_ID = 20 on gfx940+ [measured m09].
// getreg imm = id | (offset<<6) | ((width-1)<<11); width=4, offset=0.
__device__ __forceinline__ int xcc_id() {
    return __builtin_amdgcn_s_getreg((3 << 11) | 20) & (NREP - 1);
}

// Detect whether edge_index buffer is int64 (values < 2^31 => high words all 0)
__global__ void detect_i64_kernel(const unsigned int* e32, int* flag) {
    unsigned v = e32[2 * threadIdx.x + 1];
    unsigned long long m = __ballot(v != 0u);
    if (threadIdx.x == 0) *flag = (m == 0ULL) ? 1 : 0;
}

// In-degree histogram into per-XCD replica; workgroup-scope atomic -> RMW in local L2
__global__ void deg_kernel(const int* __restrict__ e32,
                           const long long* __restrict__ e64,
                           const int* __restrict__ flag,
                           int* __restrict__ deg_r) {
    int e = blockIdx.x * blockDim.x + threadIdx.x;
    if (e >= NE) return;
    int col = (*flag) ? (int)e64[NE + e] : e32[NE + e];
    int* p = deg_r + (size_t)xcc_id() * NN + col;
    __hip_atomic_fetch_add(p, 1, __ATOMIC_RELAXED, __HIP_MEMORY_SCOPE_WORKGROUP);
}

// dinv[i] = rsqrt(1 + sum_r deg_r[r][i])   (coalesced replica merge)
__global__ void dinv_kernel(const int* __restrict__ deg_r, float* __restrict__ dinv) {
    int i = blockIdx.x * blockDim.x + threadIdx.x;
    if (i >= NN) return;
    int d = 1;
#pragma unroll
    for (int r = 0; r < NREP; ++r) d += deg_r[(size_t)r * NN + i];
    dinv[i] = rsqrtf((float)d);
}

// One wave per node: g[i] = dot(x[i,:], W) * dinv[i]
__global__ __launch_bounds__(256) void node_kernel(const float* __restrict__ x,
                                                   const float* __restrict__ W,
                                                   const float* __restrict__ dinv,
                                                   float* __restrict__ g) {
    int wave = (int)((blockIdx.x * blockDim.x + threadIdx.x) >> 6);
    int lane = threadIdx.x & 63;
    if (wave >= NN) return;
    const float4* xr = (const float4*)(x + (size_t)wave * CF);
    const float4* Wr = (const float4*)W;
    float sum = 0.f;
#pragma unroll
    for (int j = 0; j < 2; ++j) {
        float4 a = xr[lane + 64 * j];
        float4 w = Wr[lane + 64 * j];
        sum += a.x * w.x + a.y * w.y + a.z * w.z + a.w * w.w;
    }
#pragma unroll
    for (int off = 32; off >= 1; off >>= 1)
        sum += __shfl_down(sum, off, 64);
    if (lane == 0) g[wave] = sum * dinv[wave];
}

// Per-edge scatter into per-XCD replica (L2-resident, workgroup-scope atomic)
__global__ void scatter_kernel(const int* __restrict__ e32,
                               const long long* __restrict__ e64,
                               const int* __restrict__ flag,
                               const float* __restrict__ g,
                               float* __restrict__ s_r) {
    int e = blockIdx.x * blockDim.x + threadIdx.x;
    if (e >= NE) return;
    int row, col;
    if (*flag) {
        row = (int)e64[e];
        col = (int)e64[NE + e];
    } else {
        row = e32[e];
        col = e32[NE + e];
    }
    float* p = s_r + (size_t)xcc_id() * NN + col;
    __hip_atomic_fetch_add(p, g[row], __ATOMIC_RELAXED, __HIP_MEMORY_SCOPE_WORKGROUP);
}

// out[i] = sigmoid(dinv[i] * (sum_r s_r[r][i] + g[i]) + b)
__global__ void final_kernel(const float* __restrict__ s_r,
                             const float* __restrict__ g,
                             const float* __restrict__ dinv,
                             const float* __restrict__ b,
                             float* __restrict__ out) {
    int i = blockIdx.x * blockDim.x + threadIdx.x;
    if (i >= NN) return;
    float s = g[i];
#pragma unroll
    for (int r = 0; r < NREP; ++r) s += s_r[(size_t)r * NN + i];
    float v = dinv[i] * s + b[0];
    out[i] = 1.f / (1.f + expf(-v));
}

extern "C" void kernel_launch(void* const* d_in, const int* in_sizes, int n_in,
                              void* d_out, int out_size, void* d_ws, size_t ws_size,
                              hipStream_t stream) {
    const float* x = (const float*)d_in[0];
    const void* eidx = d_in[1];
    const float* W = (const float*)d_in[2];
    const float* b = (const float*)d_in[3];
    float* out = (float*)d_out;

    char* ws = (char*)d_ws;
    int* deg_r = (int*)(ws);
    float* s_r = (float*)(ws + OFF_S);
    float* g = (float*)(ws + OFF_G);
    float* dinv = (float*)(ws + OFF_DINV);
    int* flag = (int*)(ws + OFF_FLAG);

    // zero deg_r + s_r replicas (ws re-poisoned to 0xAA before every call)
    hipMemsetAsync(d_ws, 0, OFF_G, stream);

    detect_i64_kernel<<<1, 64, 0, stream>>>((const unsigned int*)eidx, flag);
    deg_kernel<<<(NE + 255) / 256, 256, 0, stream>>>(
        (const int*)eidx, (const long long*)eidx, flag, deg_r);
    dinv_kernel<<<(NN + 255) / 256, 256, 0, stream>>>(deg_r, dinv);
    node_kernel<<<(NN * 64 + 255) / 256, 256, 0, stream>>>(x, W, dinv, g);
    scatter_kernel<<<(NE + 255) / 256, 256, 0, stream>>>(
        (const int*)eidx, (const long long*)eidx, flag, g, s_r);
    final_kernel<<<(NN + 255) / 256, 256, 0, stream>>>(s_r, g, dinv, b, out);
}

// Round 4
// 562.831 us; speedup vs baseline: 1.0370x; 1.0124x over previous
//
#include <hip/hip_runtime.h>
#include <hip/hip_bf16.h>
#include <math.h>

#define NN 100000
#define NE 3200000
#define CF 512

#define NPARTS  8
#define PART    12500              // nodes per partition (50 KB LDS)
#define NSLICES 16                 // edge slices
#define EPB     (NE / NSLICES)     // 200000 edges per block
#define NPB     (NSLICES * NPARTS) // 128 blocks

// ---- ws layout (bytes), total 7,200,004 (<= proven-safe R2 footprint) ----
// part  : int/float[NSLICES*NPARTS][PART] @ 0          (6,400,000)  -- reused: deg then s
// g     : float[NN]                       @ 6,400,000  (400,000)
// dinv  : float[NN]                       @ 6,800,000  (400,000)
// flag  : int                             @ 7,200,000
#define OFF_G    6400000
#define OFF_DINV 6800000
#define OFF_FLAG 7200000

// Detect int64 edge_index layout (values < 2^31 => high words all zero)
__global__ void detect_i64_kernel(const unsigned int* e32, int* flag) {
    unsigned v = e32[2 * threadIdx.x + 1];
    unsigned long long m = __ballot(v != 0u);
    if (threadIdx.x == 0) *flag = (m == 0ULL) ? 1 : 0;
}

__device__ __forceinline__ int load_col(const int* e32, bool f64, int e) {
    return f64 ? e32[2 * (NE + e)] : e32[NE + e];
}
__device__ __forceinline__ int load_row(const int* e32, bool f64, int e) {
    return f64 ? e32[2 * e] : e32[e];
}

// In-degree histogram: LDS-privatized per node-partition, partials out coalesced
__global__ __launch_bounds__(1024) void deg_lds_kernel(const int* __restrict__ e32,
                                                       const int* __restrict__ flag,
                                                       int* __restrict__ deg_part) {
    __shared__ int h[PART];
    int tid = threadIdx.x;
    for (int i = tid; i < PART; i += 1024) h[i] = 0;
    __syncthreads();
    int p = blockIdx.x & (NPARTS - 1);
    int s = blockIdx.x >> 3;
    int lo = p * PART;
    bool f64 = (*flag) != 0;
    int base = s * EPB;
    for (int e = base + tid; e < base + EPB; e += 1024) {
        unsigned l = (unsigned)(load_col(e32, f64, e) - lo);
        if (l < PART) atomicAdd(&h[l], 1);
    }
    __syncthreads();
    int* out = deg_part + (size_t)blockIdx.x * PART;
    for (int i = tid; i < PART; i += 1024) out[i] = h[i];
}

// dinv[i] = rsqrt(1 + sum_slices deg_part[.][i])
__global__ void dinv_kernel(const int* __restrict__ deg_part, float* __restrict__ dinv) {
    int i = blockIdx.x * blockDim.x + threadIdx.x;
    if (i >= NN) return;
    int p = i / PART, l = i % PART;
    int d = 1;
#pragma unroll
    for (int s = 0; s < NSLICES; ++s)
        d += deg_part[((size_t)(s * NPARTS + p)) * PART + l];
    dinv[i] = rsqrtf((float)d);
}

// One wave per node: g[i] = dot(x[i,:], W) * dinv[i]
__global__ __launch_bounds__(256) void node_kernel(const float* __restrict__ x,
                                                   const float* __restrict__ W,
                                                   const float* __restrict__ dinv,
                                                   float* __restrict__ g) {
    int wave = (int)((blockIdx.x * blockDim.x + threadIdx.x) >> 6);
    int lane = threadIdx.x & 63;
    if (wave >= NN) return;
    const float4* xr = (const float4*)(x + (size_t)wave * CF);
    const float4* Wr = (const float4*)W;
    float sum = 0.f;
#pragma unroll
    for (int j = 0; j < 2; ++j) {
        float4 a = xr[lane + 64 * j];
        float4 w = Wr[lane + 64 * j];
        sum += a.x * w.x + a.y * w.y + a.z * w.z + a.w * w.w;
    }
#pragma unroll
    for (int off = 32; off >= 1; off >>= 1)
        sum += __shfl_down(sum, off, 64);
    if (lane == 0) g[wave] = sum * dinv[wave];
}

// Edge scatter: s[col] += g[row], LDS-privatized, partials out coalesced
__global__ __launch_bounds__(1024) void scatter_lds_kernel(const int* __restrict__ e32,
                                                           const int* __restrict__ flag,
                                                           const float* __restrict__ g,
                                                           float* __restrict__ s_part) {
    __shared__ float h[PART];
    int tid = threadIdx.x;
    for (int i = tid; i < PART; i += 1024) h[i] = 0.f;
    __syncthreads();
    int p = blockIdx.x & (NPARTS - 1);
    int s = blockIdx.x >> 3;
    int lo = p * PART;
    bool f64 = (*flag) != 0;
    int base = s * EPB;
    for (int e = base + tid; e < base + EPB; e += 1024) {
        unsigned l = (unsigned)(load_col(e32, f64, e) - lo);
        if (l < PART) {
            int row = load_row(e32, f64, e);
            atomicAdd(&h[l], g[row]);
        }
    }
    __syncthreads();
    float* out = s_part + (size_t)blockIdx.x * PART;
    for (int i = tid; i < PART; i += 1024) out[i] = h[i];
}

// out[i] = sigmoid(dinv[i] * (sum_slices s_part[.][i] + g[i]) + b)
__global__ void final_kernel(const float* __restrict__ s_part,
                             const float* __restrict__ g,
                             const float* __restrict__ dinv,
                             const float* __restrict__ b,
                             float* __restrict__ out) {
    int i = blockIdx.x * blockDim.x + threadIdx.x;
    if (i >= NN) return;
    int p = i / PART, l = i % PART;
    float acc = g[i];
#pragma unroll
    for (int s = 0; s < NSLICES; ++s)
        acc += s_part[((size_t)(s * NPARTS + p)) * PART + l];
    float v = dinv[i] * acc + b[0];
    out[i] = 1.f / (1.f + expf(-v));
}

extern "C" void kernel_launch(void* const* d_in, const int* in_sizes, int n_in,
                              void* d_out, int out_size, void* d_ws, size_t ws_size,
                              hipStream_t stream) {
    const float* x = (const float*)d_in[0];
    const int* eidx = (const int*)d_in[1];
    const float* W = (const float*)d_in[2];
    const float* b = (const float*)d_in[3];
    float* out = (float*)d_out;

    char* ws = (char*)d_ws;
    int* part_i = (int*)(ws);            // deg partials (then reused as s partials)
    float* part_f = (float*)(ws);
    float* g = (float*)(ws + OFF_G);
    float* dinv = (float*)(ws + OFF_DINV);
    int* flag = (int*)(ws + OFF_FLAG);

    detect_i64_kernel<<<1, 64, 0, stream>>>((const unsigned int*)eidx, flag);
    deg_lds_kernel<<<NPB, 1024, 0, stream>>>(eidx, flag, part_i);
    dinv_kernel<<<(NN + 255) / 256, 256, 0, stream>>>(part_i, dinv);
    node_kernel<<<(NN * 64 + 255) / 256, 256, 0, stream>>>(x, W, dinv, g);
    scatter_lds_kernel<<<NPB, 1024, 0, stream>>>(eidx, flag, g, part_f);
    final_kernel<<<(NN + 255) / 256, 256, 0, stream>>>(part_f, g, dinv, b, out);
}

// Round 5
// 369.929 us; speedup vs baseline: 1.5778x; 1.5215x over previous
//
#include <hip/hip_runtime.h>
#include <hip/hip_fp16.h>
#include <math.h>

#define NN 100000
#define NE 3200000
#define CF 512

#define NPARTS  8
#define PART    12500              // nodes per partition (50 KB LDS hist)
#define NSLICES 32                 // edge slices
#define EPB     (NE / NSLICES)     // 100000 edges per block
#define NPB     (NSLICES * NPARTS) // 256 blocks

// ---- ws layout (bytes), total 7,200,004 (proven-safe footprint) ----
// part : i16/half [NPB][PART] @ 0          (6,400,000)  -- reused: deg(i16) then s(half)
// g    : float[NN]            @ 6,400,000  (400,000)
// dinv : float[NN]            @ 6,800,000  (400,000)
// flag : int                  @ 7,200,000
#define OFF_G    6400000
#define OFF_DINV 6800000
#define OFF_FLAG 7200000

// Detect int64 edge_index layout (values < 2^31 => high words all zero)
__global__ void detect_i64_kernel(const unsigned int* e32, int* flag) {
    unsigned v = e32[2 * threadIdx.x + 1];
    unsigned long long m = __ballot(v != 0u);
    if (threadIdx.x == 0) *flag = (m == 0ULL) ? 1 : 0;
}

// Load 4 consecutive cols starting at edge e (e % 4 == 0)
__device__ __forceinline__ int4 load_col4(const int* __restrict__ e32, bool f64, int e) {
    if (f64) {
        const int4* q = (const int4*)(e32 + 2 * (NE + e));  // 2 int64 per int4
        int4 a = q[0], b = q[1];
        return make_int4(a.x, a.z, b.x, b.z);
    }
    return *(const int4*)(e32 + NE + e);
}
__device__ __forceinline__ int load_row(const int* __restrict__ e32, bool f64, int e) {
    return f64 ? e32[2 * e] : e32[e];
}

// In-degree histogram: LDS-privatized per node-partition, int16 partials out.
// Block swizzle: p = blk>>5, s = blk&31 -> the 8 sibling blocks of a slice share
// an XCD (ids congruent mod 8) and thus its L2 for the col stream.
__global__ __launch_bounds__(1024) void deg_lds_kernel(const int* __restrict__ e32,
                                                       const int* __restrict__ flag,
                                                       short* __restrict__ deg_part) {
    __shared__ int h[PART];
    int tid = threadIdx.x;
    for (int i = tid; i < PART; i += 1024) h[i] = 0;
    __syncthreads();
    int p = blockIdx.x >> 5;
    int s = blockIdx.x & 31;
    int lo = p * PART;
    bool f64 = (*flag) != 0;
    int base = s * EPB;
    for (int e = base + tid * 4; e < base + EPB; e += 4096) {
        int4 c = load_col4(e32, f64, e);
        unsigned l0 = (unsigned)(c.x - lo), l1 = (unsigned)(c.y - lo);
        unsigned l2 = (unsigned)(c.z - lo), l3 = (unsigned)(c.w - lo);
        if (l0 < PART) atomicAdd(&h[l0], 1);
        if (l1 < PART) atomicAdd(&h[l1], 1);
        if (l2 < PART) atomicAdd(&h[l2], 1);
        if (l3 < PART) atomicAdd(&h[l3], 1);
    }
    __syncthreads();
    short* out = deg_part + (size_t)blockIdx.x * PART;
    for (int i = tid; i < PART; i += 1024) out[i] = (short)h[i];
}

// dinv[i] = rsqrt(1 + sum_slices deg_part[.][i])
__global__ void dinv_kernel(const short* __restrict__ deg_part, float* __restrict__ dinv) {
    int i = blockIdx.x * blockDim.x + threadIdx.x;
    if (i >= NN) return;
    int p = i / PART, l = i - p * PART;
    const short* bp = deg_part + ((size_t)(p << 5)) * PART + l;
    int d = 1;
#pragma unroll
    for (int s = 0; s < NSLICES; ++s) d += bp[(size_t)s * PART];
    dinv[i] = rsqrtf((float)d);
}

// One wave per node: g[i] = dot(x[i,:], W) * dinv[i]
__global__ __launch_bounds__(256) void node_kernel(const float* __restrict__ x,
                                                   const float* __restrict__ W,
                                                   const float* __restrict__ dinv,
                                                   float* __restrict__ g) {
    int wave = (int)((blockIdx.x * blockDim.x + threadIdx.x) >> 6);
    int lane = threadIdx.x & 63;
    if (wave >= NN) return;
    const float4* xr = (const float4*)(x + (size_t)wave * CF);
    const float4* Wr = (const float4*)W;
    float sum = 0.f;
#pragma unroll
    for (int j = 0; j < 2; ++j) {
        float4 a = xr[lane + 64 * j];
        float4 w = Wr[lane + 64 * j];
        sum += a.x * w.x + a.y * w.y + a.z * w.z + a.w * w.w;
    }
#pragma unroll
    for (int off = 32; off >= 1; off >>= 1)
        sum += __shfl_down(sum, off, 64);
    if (lane == 0) g[wave] = sum * dinv[wave];
}

// Edge scatter: s[col] += g[row], LDS-privatized, half partials out
__global__ __launch_bounds__(1024) void scatter_lds_kernel(const int* __restrict__ e32,
                                                           const int* __restrict__ flag,
                                                           const float* __restrict__ g,
                                                           __half* __restrict__ s_part) {
    __shared__ float h[PART];
    int tid = threadIdx.x;
    for (int i = tid; i < PART; i += 1024) h[i] = 0.f;
    __syncthreads();
    int p = blockIdx.x >> 5;
    int s = blockIdx.x & 31;
    int lo = p * PART;
    bool f64 = (*flag) != 0;
    int base = s * EPB;
    for (int e = base + tid * 4; e < base + EPB; e += 4096) {
        int4 c = load_col4(e32, f64, e);
        unsigned l0 = (unsigned)(c.x - lo), l1 = (unsigned)(c.y - lo);
        unsigned l2 = (unsigned)(c.z - lo), l3 = (unsigned)(c.w - lo);
        if (l0 < PART) atomicAdd(&h[l0], g[load_row(e32, f64, e + 0)]);
        if (l1 < PART) atomicAdd(&h[l1], g[load_row(e32, f64, e + 1)]);
        if (l2 < PART) atomicAdd(&h[l2], g[load_row(e32, f64, e + 2)]);
        if (l3 < PART) atomicAdd(&h[l3], g[load_row(e32, f64, e + 3)]);
    }
    __syncthreads();
    __half* out = s_part + (size_t)blockIdx.x * PART;
    for (int i = tid; i < PART; i += 1024) out[i] = __float2half(h[i]);
}

// out[i] = sigmoid(dinv[i] * (sum_slices s_part[.][i] + g[i]) + b)
__global__ void final_kernel(const __half* __restrict__ s_part,
                             const float* __restrict__ g,
                             const float* __restrict__ dinv,
                             const float* __restrict__ b,
                             float* __restrict__ out) {
    int i = blockIdx.x * blockDim.x + threadIdx.x;
    if (i >= NN) return;
    int p = i / PART, l = i - p * PART;
    const __half* bp = s_part + ((size_t)(p << 5)) * PART + l;
    float acc = g[i];
#pragma unroll
    for (int s = 0; s < NSLICES; ++s) acc += __half2float(bp[(size_t)s * PART]);
    float v = dinv[i] * acc + b[0];
    out[i] = 1.f / (1.f + expf(-v));
}

extern "C" void kernel_launch(void* const* d_in, const int* in_sizes, int n_in,
                              void* d_out, int out_size, void* d_ws, size_t ws_size,
                              hipStream_t stream) {
    const float* x = (const float*)d_in[0];
    const int* eidx = (const int*)d_in[1];
    const float* W = (const float*)d_in[2];
    const float* b = (const float*)d_in[3];
    float* out = (float*)d_out;

    char* ws = (char*)d_ws;
    short* part_i16 = (short*)(ws);      // deg partials (reused as half s partials)
    __half* part_h = (__half*)(ws);
    float* g = (float*)(ws + OFF_G);
    float* dinv = (float*)(ws + OFF_DINV);
    int* flag = (int*)(ws + OFF_FLAG);

    detect_i64_kernel<<<1, 64, 0, stream>>>((const unsigned int*)eidx, flag);
    deg_lds_kernel<<<NPB, 1024, 0, stream>>>(eidx, flag, part_i16);
    dinv_kernel<<<(NN + 255) / 256, 256, 0, stream>>>(part_i16, dinv);
    node_kernel<<<(NN * 64 + 255) / 256, 256, 0, stream>>>(x, W, dinv, g);
    scatter_lds_kernel<<<NPB, 1024, 0, stream>>>(eidx, flag, g, part_h);
    final_kernel<<<(NN + 255) / 256, 256, 0, stream>>>(part_h, g, dinv, b, out);
}

// Round 6
// 364.677 us; speedup vs baseline: 1.6005x; 1.0144x over previous
//
#include <hip/hip_runtime.h>
#include <hip/hip_fp16.h>
#include <math.h>

#define NN 100000
#define NE 3200000
#define CF 512

#define NPARTS  8
#define PART    12500              // nodes per partition (50 KB LDS hist)
#define NSLICES 64                 // edge slices
#define EPB     (NE / NSLICES)     // 50000 edges per block
#define NPB     (NSLICES * NPARTS) // 512 blocks -> 2 blocks/CU, 100% occupancy

// ---- ws layout (bytes), total 13,600,004 (ws_size ~800 MB per R5 profile) ----
// part : u16/half [NPB][PART] @ 0           (12,800,000) -- reused: deg(u16) then s(half)
// g    : float[NN]            @ 12,800,000  (400,000)
// dinv : float[NN]            @ 13,200,000  (400,000)
// flag : int                  @ 13,600,000
#define OFF_G    12800000
#define OFF_DINV 13200000
#define OFF_FLAG 13600000

// Detect int64 edge_index layout (values < 2^31 => high words all zero)
__global__ void detect_i64_kernel(const unsigned int* e32, int* flag) {
    unsigned v = e32[2 * threadIdx.x + 1];
    unsigned long long m = __ballot(v != 0u);
    if (threadIdx.x == 0) *flag = (m == 0ULL) ? 1 : 0;
}

// Load 4 consecutive cols starting at edge e (e % 4 == 0)
__device__ __forceinline__ int4 load_col4(const int* __restrict__ e32, bool f64, int e) {
    if (f64) {
        const int4* q = (const int4*)(e32 + 2 * (NE + e));  // 2 int64 per int4
        int4 a = q[0], b = q[1];
        return make_int4(a.x, a.z, b.x, b.z);
    }
    return *(const int4*)(e32 + NE + e);
}
__device__ __forceinline__ int load_row(const int* __restrict__ e32, bool f64, int e) {
    return f64 ? e32[2 * e] : e32[e];
}

// In-degree histogram: LDS-privatized per node-partition, u16 partials out.
// Swizzle: p = blk>>6, s = blk&63 -> the 8 partition-siblings of a slice have
// ids congruent mod 8 -> same XCD -> shared L2 for the col stream.
__global__ __launch_bounds__(1024) void deg_lds_kernel(const int* __restrict__ e32,
                                                       const int* __restrict__ flag,
                                                       unsigned short* __restrict__ deg_part) {
    __shared__ int h[PART];
    int tid = threadIdx.x;
    for (int i = tid; i < PART; i += 1024) h[i] = 0;
    __syncthreads();
    int p = blockIdx.x >> 6;
    int s = blockIdx.x & 63;
    int lo = p * PART;
    bool f64 = (*flag) != 0;
    int base = s * EPB;
    for (int e = base + tid * 4; e < base + EPB; e += 4096) {
        int4 c = load_col4(e32, f64, e);
        unsigned l0 = (unsigned)(c.x - lo), l1 = (unsigned)(c.y - lo);
        unsigned l2 = (unsigned)(c.z - lo), l3 = (unsigned)(c.w - lo);
        if (l0 < PART) atomicAdd(&h[l0], 1);
        if (l1 < PART) atomicAdd(&h[l1], 1);
        if (l2 < PART) atomicAdd(&h[l2], 1);
        if (l3 < PART) atomicAdd(&h[l3], 1);
    }
    __syncthreads();
    unsigned short* out = deg_part + (size_t)blockIdx.x * PART;
    for (int i = tid; i < PART; i += 1024) out[i] = (unsigned short)h[i];
}

// dinv[i] = rsqrt(1 + sum_slices deg_part[.][i])
__global__ void dinv_kernel(const unsigned short* __restrict__ deg_part,
                            float* __restrict__ dinv) {
    int i = blockIdx.x * blockDim.x + threadIdx.x;
    if (i >= NN) return;
    int p = i / PART, l = i - p * PART;
    const unsigned short* bp = deg_part + ((size_t)(p << 6)) * PART + l;
    int d = 1;
#pragma unroll
    for (int s = 0; s < NSLICES; ++s) d += bp[(size_t)s * PART];
    dinv[i] = rsqrtf((float)d);
}

// One wave per node: g[i] = dot(x[i,:], W) * dinv[i]
__global__ __launch_bounds__(256) void node_kernel(const float* __restrict__ x,
                                                   const float* __restrict__ W,
                                                   const float* __restrict__ dinv,
                                                   float* __restrict__ g) {
    int wave = (int)((blockIdx.x * blockDim.x + threadIdx.x) >> 6);
    int lane = threadIdx.x & 63;
    if (wave >= NN) return;
    const float4* xr = (const float4*)(x + (size_t)wave * CF);
    const float4* Wr = (const float4*)W;
    float sum = 0.f;
#pragma unroll
    for (int j = 0; j < 2; ++j) {
        float4 a = xr[lane + 64 * j];
        float4 w = Wr[lane + 64 * j];
        sum += a.x * w.x + a.y * w.y + a.z * w.z + a.w * w.w;
    }
#pragma unroll
    for (int off = 32; off >= 1; off >>= 1)
        sum += __shfl_down(sum, off, 64);
    if (lane == 0) g[wave] = sum * dinv[wave];
}

// Edge scatter: s[col] += g[row], LDS-privatized, half partials out
__global__ __launch_bounds__(1024) void scatter_lds_kernel(const int* __restrict__ e32,
                                                           const int* __restrict__ flag,
                                                           const float* __restrict__ g,
                                                           __half* __restrict__ s_part) {
    __shared__ float h[PART];
    int tid = threadIdx.x;
    for (int i = tid; i < PART; i += 1024) h[i] = 0.f;
    __syncthreads();
    int p = blockIdx.x >> 6;
    int s = blockIdx.x & 63;
    int lo = p * PART;
    bool f64 = (*flag) != 0;
    int base = s * EPB;
    for (int e = base + tid * 4; e < base + EPB; e += 4096) {
        int4 c = load_col4(e32, f64, e);
        unsigned l0 = (unsigned)(c.x - lo), l1 = (unsigned)(c.y - lo);
        unsigned l2 = (unsigned)(c.z - lo), l3 = (unsigned)(c.w - lo);
        if (l0 < PART) atomicAdd(&h[l0], g[load_row(e32, f64, e + 0)]);
        if (l1 < PART) atomicAdd(&h[l1], g[load_row(e32, f64, e + 1)]);
        if (l2 < PART) atomicAdd(&h[l2], g[load_row(e32, f64, e + 2)]);
        if (l3 < PART) atomicAdd(&h[l3], g[load_row(e32, f64, e + 3)]);
    }
    __syncthreads();
    __half* out = s_part + (size_t)blockIdx.x * PART;
    for (int i = tid; i < PART; i += 1024) out[i] = __float2half(h[i]);
}

// out[i] = sigmoid(dinv[i] * (sum_slices s_part[.][i] + g[i]) + b)
__global__ void final_kernel(const __half* __restrict__ s_part,
                             const float* __restrict__ g,
                             const float* __restrict__ dinv,
                             const float* __restrict__ b,
                             float* __restrict__ out) {
    int i = blockIdx.x * blockDim.x + threadIdx.x;
    if (i >= NN) return;
    int p = i / PART, l = i - p * PART;
    const __half* bp = s_part + ((size_t)(p << 6)) * PART + l;
    float acc = g[i];
#pragma unroll
    for (int s = 0; s < NSLICES; ++s) acc += __half2float(bp[(size_t)s * PART]);
    float v = dinv[i] * acc + b[0];
    out[i] = 1.f / (1.f + expf(-v));
}

extern "C" void kernel_launch(void* const* d_in, const int* in_sizes, int n_in,
                              void* d_out, int out_size, void* d_ws, size_t ws_size,
                              hipStream_t stream) {
    const float* x = (const float*)d_in[0];
    const int* eidx = (const int*)d_in[1];
    const float* W = (const float*)d_in[2];
    const float* b = (const float*)d_in[3];
    float* out = (float*)d_out;

    char* ws = (char*)d_ws;
    unsigned short* part_u16 = (unsigned short*)(ws);  // deg partials (reused as half)
    __half* part_h = (__half*)(ws);
    float* g = (float*)(ws + OFF_G);
    float* dinv = (float*)(ws + OFF_DINV);
    int* flag = (int*)(ws + OFF_FLAG);

    detect_i64_kernel<<<1, 64, 0, stream>>>((const unsigned int*)eidx, flag);
    deg_lds_kernel<<<NPB, 1024, 0, stream>>>(eidx, flag, part_u16);
    dinv_kernel<<<(NN + 255) / 256, 256, 0, stream>>>(part_u16, dinv);
    node_kernel<<<(NN * 64 + 255) / 256, 256, 0, stream>>>(x, W, dinv, g);
    scatter_lds_kernel<<<NPB, 1024, 0, stream>>>(eidx, flag, g, part_h);
    final_kernel<<<(NN + 255) / 256, 256, 0, stream>>>(part_h, g, dinv, b, out);
}